// Round 1
// baseline (3129.571 us; speedup 1.0000x reference)
//
#include <hip/hip_runtime.h>
#include <hip/hip_bf16.h>
#include <math.h>

#define NN 20000
#define DEGV 16
#define CINV 128
#define TSTEPS 3
#define HIDV 128

// ---------------------------------------------------------------------------
// Kernel 1: P[n][s][j] = sum_k v[n][k] * W1[(s*128+k)*64 + j]   (s=0..3, j=0..63)
// also init base[n][j] = P[n][0][j] + b1[j], walk_idx[0][n] = n
// ---------------------------------------------------------------------------
__global__ __launch_bounds__(256) void k_precompute(
    const float* __restrict__ v, const float* __restrict__ W1,
    const float* __restrict__ b1,
    float* __restrict__ P, float* __restrict__ base, int* __restrict__ walk_idx)
{
    __shared__ float vt[16][132];
    int nb = blockIdx.x * 16;
    for (int idx = threadIdx.x; idx < 16 * 128; idx += 256) {
        int nl = idx >> 7, k = idx & 127;
        int n = nb + nl;
        vt[nl][k] = (n < NN) ? v[n * 128 + k] : 0.f;
    }
    __syncthreads();
    int s = threadIdx.x >> 6;   // 0..3 (slot)
    int j = threadIdx.x & 63;   // 0..63 (mlp hidden)
    double acc[16];
#pragma unroll
    for (int nl = 0; nl < 16; ++nl) acc[nl] = 0.0;
    for (int k = 0; k < 128; ++k) {
        double w = (double)W1[(s * 128 + k) * 64 + j];
#pragma unroll
        for (int nl = 0; nl < 16; ++nl)
            acc[nl] = fma((double)vt[nl][k], w, acc[nl]);
    }
    for (int nl = 0; nl < 16; ++nl) {
        int n = nb + nl;
        if (n < NN) {
            float pv = (float)acc[nl];
            P[n * 256 + s * 64 + j] = pv;
            if (s == 0) {
                base[n * 64 + j] = pv + b1[j];
                if (j == 0) walk_idx[n] = n;
            }
        }
    }
}

// ---------------------------------------------------------------------------
// Kernel 2: one walk selection step. One 64-lane wave per node.
//   lane = d*4 + sub : candidate d (0..15), sub-slice sub (0..3) of the 64-dim dot
// ---------------------------------------------------------------------------
__global__ __launch_bounds__(256) void k_walk_step(
    const float* __restrict__ P, float* __restrict__ base,
    const int* __restrict__ dst, const float* __restrict__ W2,
    const float* __restrict__ b2, const float* __restrict__ noise,
    int* __restrict__ walk_idx, int t)
{
    int wave = threadIdx.x >> 6;
    int lane = threadIdx.x & 63;
    int n = blockIdx.x * 4 + wave;
    if (n >= NN) return;

    int wl = walk_idx[t * NN + n];
    int d = lane >> 2, sub = lane & 3;
    int cand = dst[wl * DEGV + d];

    const float4* b4 = (const float4*)(base + (size_t)n * 64);
    const float4* p4 = (const float4*)(P + (size_t)cand * 256 + (t + 1) * 64);
    const float4* w4 = (const float4*)W2;

    double acc = 0.0;
#pragma unroll
    for (int k = 0; k < 4; ++k) {
        float4 bb = b4[sub * 4 + k];
        float4 pp = p4[sub * 4 + k];
        float4 ww = w4[sub * 4 + k];
        acc += (double)fmaxf(bb.x + pp.x, 0.f) * (double)ww.x;
        acc += (double)fmaxf(bb.y + pp.y, 0.f) * (double)ww.y;
        acc += (double)fmaxf(bb.z + pp.z, 0.f) * (double)ww.z;
        acc += (double)fmaxf(bb.w + pp.w, 0.f) * (double)ww.w;
    }
    // reduce the 4 sub-slices -> logp for candidate d (all 4 lanes of the group)
    acc += __shfl_xor(acc, 1);
    acc += __shfl_xor(acc, 2);
    double logp = acc + (double)b2[0];

    // logsumexp across the 16 candidate groups (bits 2..5 of lane)
    double m = logp;
    for (int mask = 4; mask < 64; mask <<= 1) m = fmax(m, __shfl_xor(m, mask));
    double e = exp(logp - m);
    double ssum = e;
    for (int mask = 4; mask < 64; mask <<= 1) ssum += __shfl_xor(ssum, mask);
    double norm = m + log(ssum);

    double wp = exp(logp - norm) +
                0.01 * (double)noise[((size_t)t * NN + n) * DEGV + d];

    // argmax with first-index tie-break (matches jnp.argmax)
    int bd = d;
    double bwp = wp;
    for (int mask = 4; mask < 64; mask <<= 1) {
        double owp = __shfl_xor(bwp, mask);
        int od = __shfl_xor(bd, mask);
        if (owp > bwp || (owp == bwp && od < bd)) { bwp = owp; bd = od; }
    }
    int sel = dst[wl * DEGV + bd];

    // base += P[sel][t+1]  (lane j handles component j)
    base[(size_t)n * 64 + lane] += P[(size_t)sel * 256 + (t + 1) * 64 + lane];
    if (lane == 0) walk_idx[(t + 1) * NN + n] = sel;
}

// ---------------------------------------------------------------------------
// Kernel 3: one GRU step. 16 nodes per block.
//   gi = x @ Wih^T + bih ; gh = h @ Whh^T + bhh (h=0 on first step)
//   r=sig(gi_r+gh_r) z=sig(gi_z+gh_z) n=tanh(gi_n + r*gh_n)
//   h' = (1-z)*n + z*h
// ---------------------------------------------------------------------------
template <int FIRST>
__global__ __launch_bounds__(256) void k_gru_step(
    const float* __restrict__ v, const int* __restrict__ walk_idx,
    const float* __restrict__ Wih, const float* __restrict__ Whh,
    const float* __restrict__ bih, const float* __restrict__ bhh,
    float* __restrict__ h, int t)
{
    __shared__ float xt[16][132];
    __shared__ float ht[16][132];
    __shared__ float gates[16][516];   // [0:128]=r-sum [128:256]=z-sum [256:384]=gi_n [384:512]=gh_n
    int nb = blockIdx.x * 16;
    for (int idx = threadIdx.x; idx < 16 * 128; idx += 256) {
        int nl = idx >> 7, k = idx & 127;
        int n = nb + nl;
        float xv = 0.f, hv = 0.f;
        if (n < NN) {
            int w = walk_idx[t * NN + n];
            xv = v[(size_t)w * 128 + k];
            if (!FIRST) hv = h[(size_t)n * 128 + k];
        }
        xt[nl][k] = xv;
        ht[nl][k] = hv;
    }
    __syncthreads();

    int nl = threadIdx.x >> 4;
    int jm = threadIdx.x & 15;
    const float4* xv4 = (const float4*)(&xt[nl][0]);
    const float4* hv4 = (const float4*)(&ht[nl][0]);
    for (int jc = 0; jc < 24; ++jc) {
        int j = jc * 16 + jm;
        float gi = bih[j], gh = bhh[j];
        const float4* wi = (const float4*)(Wih + (size_t)j * 128);
        const float4* wh = (const float4*)(Whh + (size_t)j * 128);
#pragma unroll 8
        for (int k = 0; k < 32; ++k) {
            float4 a = xv4[k], wa = wi[k];
            gi = fmaf(a.x, wa.x, gi); gi = fmaf(a.y, wa.y, gi);
            gi = fmaf(a.z, wa.z, gi); gi = fmaf(a.w, wa.w, gi);
            if (!FIRST) {
                float4 b = hv4[k], wb = wh[k];
                gh = fmaf(b.x, wb.x, gh); gh = fmaf(b.y, wb.y, gh);
                gh = fmaf(b.z, wb.z, gh); gh = fmaf(b.w, wb.w, gh);
            }
        }
        int g = j >> 7, u = j & 127;
        if (g == 0)       gates[nl][u]        = gi + gh;
        else if (g == 1)  gates[nl][128 + u]  = gi + gh;
        else            { gates[nl][256 + u]  = gi;
                          gates[nl][384 + u]  = gh; }
    }
    __syncthreads();

    for (int e = threadIdx.x; e < 16 * 128; e += 256) {
        int nl2 = e >> 7, u = e & 127;
        int n = nb + nl2;
        if (n < NN) {
            float r = 1.f / (1.f + expf(-gates[nl2][u]));
            float z = 1.f / (1.f + expf(-gates[nl2][128 + u]));
            float nn = tanhf(fmaf(r, gates[nl2][384 + u], gates[nl2][256 + u]));
            float hp = ht[nl2][u];
            h[(size_t)n * 128 + u] = (1.f - z) * nn + z * hp;
        }
    }
}

// ---------------------------------------------------------------------------
// Kernel 4: out = h @ Wout + bout
// ---------------------------------------------------------------------------
__global__ __launch_bounds__(256) void k_out(
    const float* __restrict__ h, const float* __restrict__ Wout,
    const float* __restrict__ bout, float* __restrict__ out)
{
    __shared__ float ht[16][132];
    int nb = blockIdx.x * 16;
    for (int idx = threadIdx.x; idx < 16 * 128; idx += 256) {
        int nl = idx >> 7, k = idx & 127;
        int n = nb + nl;
        ht[nl][k] = (n < NN) ? h[(size_t)n * 128 + k] : 0.f;
    }
    __syncthreads();
    int nl = threadIdx.x >> 4;
    int om = threadIdx.x & 15;
    int n = nb + nl;
    for (int oc = 0; oc < 8; ++oc) {
        int o = oc * 16 + om;
        float acc = bout[o];
        for (int k = 0; k < 128; ++k)
            acc = fmaf(ht[nl][k], Wout[k * 128 + o], acc);
        if (n < NN) out[(size_t)n * 128 + o] = acc;
    }
}

// ---------------------------------------------------------------------------
extern "C" void kernel_launch(void* const* d_in, const int* in_sizes, int n_in,
                              void* d_out, int out_size, void* d_ws, size_t ws_size,
                              hipStream_t stream)
{
    const float* node_attr = (const float*)d_in[0];
    const int*   edge_index = (const int*)d_in[1];
    const float* W1  = (const float*)d_in[3];
    const float* b1  = (const float*)d_in[4];
    const float* W2  = (const float*)d_in[5];
    const float* b2  = (const float*)d_in[6];
    const float* Wih = (const float*)d_in[7];
    const float* Whh = (const float*)d_in[8];
    const float* bih = (const float*)d_in[9];
    const float* bhh = (const float*)d_in[10];
    const float* Wout = (const float*)d_in[11];
    const float* bout = (const float*)d_in[12];
    const float* noise = (const float*)d_in[13];

    const int* dst = edge_index + (size_t)NN * DEGV;  // row 1 of edge_index

    char* ws = (char*)d_ws;
    size_t offP    = 0;                               // N*256 f32 = 20.48 MB
    size_t offBase = offP + (size_t)NN * 256 * 4;     // N*64 f32  =  5.12 MB
    size_t offH    = offBase + (size_t)NN * 64 * 4;   // N*128 f32 = 10.24 MB
    size_t offWidx = offH + (size_t)NN * 128 * 4;     // 4*N int   =  0.32 MB
    float* P    = (float*)(ws + offP);
    float* base = (float*)(ws + offBase);
    float* h    = (float*)(ws + offH);
    int*   widx = (int*)(ws + offWidx);

    dim3 blk(256);
    // 1) per-node/per-slot MLP partials + init
    k_precompute<<<dim3(1250), blk, 0, stream>>>(node_attr, W1, b1, P, base, widx);
    // 2) 3 walk-selection steps (sequential dependency)
    for (int t = 0; t < TSTEPS; ++t)
        k_walk_step<<<dim3(5000), blk, 0, stream>>>(P, base, dst, W2, b2, noise, widx, t);
    // 3) GRU over the 4-slot walk sequence
    k_gru_step<1><<<dim3(1250), blk, 0, stream>>>(node_attr, widx, Wih, Whh, bih, bhh, h, 0);
    for (int t = 1; t <= TSTEPS; ++t)
        k_gru_step<0><<<dim3(1250), blk, 0, stream>>>(node_attr, widx, Wih, Whh, bih, bhh, h, t);
    // 4) output projection
    k_out<<<dim3(1250), blk, 0, stream>>>(h, Wout, bout, (float*)d_out);
}

// Round 2
// 648.147 us; speedup vs baseline: 4.8285x; 4.8285x over previous
//
#include <hip/hip_runtime.h>
#include <hip/hip_bf16.h>
#include <math.h>

#define NN 20000
#define DEGV 16
#define CINV 128
#define TSTEPS 3
#define HIDV 128

typedef float f32x4 __attribute__((ext_vector_type(4)));
typedef short s16x8 __attribute__((ext_vector_type(8)));

#define MFMA16(a, b, c) __builtin_amdgcn_mfma_f32_16x16x32_bf16(a, b, c, 0, 0, 0)

static __device__ __forceinline__ short f2bf(float x) {
    __hip_bfloat16 h = __float2bfloat16(x);
    return *reinterpret_cast<short*>(&h);
}

// ---------------------------------------------------------------------------
// Kernel 1 (unchanged): P[n][s][j] = sum_k v[n][k] * W1[(s*128+k)*64 + j]
// also init base[n][j] = P[n][0][j] + b1[j], walk_idx[0][n] = n
// ---------------------------------------------------------------------------
__global__ __launch_bounds__(256) void k_precompute(
    const float* __restrict__ v, const float* __restrict__ W1,
    const float* __restrict__ b1,
    float* __restrict__ P, float* __restrict__ base, int* __restrict__ walk_idx)
{
    __shared__ float vt[16][132];
    int nb = blockIdx.x * 16;
    for (int idx = threadIdx.x; idx < 16 * 128; idx += 256) {
        int nl = idx >> 7, k = idx & 127;
        int n = nb + nl;
        vt[nl][k] = (n < NN) ? v[n * 128 + k] : 0.f;
    }
    __syncthreads();
    int s = threadIdx.x >> 6;
    int j = threadIdx.x & 63;
    double acc[16];
#pragma unroll
    for (int nl = 0; nl < 16; ++nl) acc[nl] = 0.0;
    for (int k = 0; k < 128; ++k) {
        double w = (double)W1[(s * 128 + k) * 64 + j];
#pragma unroll
        for (int nl = 0; nl < 16; ++nl)
            acc[nl] = fma((double)vt[nl][k], w, acc[nl]);
    }
    for (int nl = 0; nl < 16; ++nl) {
        int n = nb + nl;
        if (n < NN) {
            float pv = (float)acc[nl];
            P[n * 256 + s * 64 + j] = pv;
            if (s == 0) {
                base[n * 64 + j] = pv + b1[j];
                if (j == 0) walk_idx[n] = n;
            }
        }
    }
}

// ---------------------------------------------------------------------------
// Kernel 2 (unchanged): one walk selection step. One 64-lane wave per node.
// ---------------------------------------------------------------------------
__global__ __launch_bounds__(256) void k_walk_step(
    const float* __restrict__ P, float* __restrict__ base,
    const int* __restrict__ dst, const float* __restrict__ W2,
    const float* __restrict__ b2, const float* __restrict__ noise,
    int* __restrict__ walk_idx, int t)
{
    int wave = threadIdx.x >> 6;
    int lane = threadIdx.x & 63;
    int n = blockIdx.x * 4 + wave;
    if (n >= NN) return;

    int wl = walk_idx[t * NN + n];
    int d = lane >> 2, sub = lane & 3;
    int cand = dst[wl * DEGV + d];

    const float4* b4 = (const float4*)(base + (size_t)n * 64);
    const float4* p4 = (const float4*)(P + (size_t)cand * 256 + (t + 1) * 64);
    const float4* w4 = (const float4*)W2;

    double acc = 0.0;
#pragma unroll
    for (int k = 0; k < 4; ++k) {
        float4 bb = b4[sub * 4 + k];
        float4 pp = p4[sub * 4 + k];
        float4 ww = w4[sub * 4 + k];
        acc += (double)fmaxf(bb.x + pp.x, 0.f) * (double)ww.x;
        acc += (double)fmaxf(bb.y + pp.y, 0.f) * (double)ww.y;
        acc += (double)fmaxf(bb.z + pp.z, 0.f) * (double)ww.z;
        acc += (double)fmaxf(bb.w + pp.w, 0.f) * (double)ww.w;
    }
    acc += __shfl_xor(acc, 1);
    acc += __shfl_xor(acc, 2);
    double logp = acc + (double)b2[0];

    double m = logp;
    for (int mask = 4; mask < 64; mask <<= 1) m = fmax(m, __shfl_xor(m, mask));
    double e = exp(logp - m);
    double ssum = e;
    for (int mask = 4; mask < 64; mask <<= 1) ssum += __shfl_xor(ssum, mask);
    double norm = m + log(ssum);

    double wp = exp(logp - norm) +
                0.01 * (double)noise[((size_t)t * NN + n) * DEGV + d];

    int bd = d;
    double bwp = wp;
    for (int mask = 4; mask < 64; mask <<= 1) {
        double owp = __shfl_xor(bwp, mask);
        int od = __shfl_xor(bd, mask);
        if (owp > bwp || (owp == bwp && od < bd)) { bwp = owp; bd = od; }
    }
    int sel = dst[wl * DEGV + bd];

    base[(size_t)n * 64 + lane] += P[(size_t)sel * 256 + (t + 1) * 64 + lane];
    if (lane == 0) walk_idx[(t + 1) * NN + n] = sel;
}

// ---------------------------------------------------------------------------
// Kernel 3: convert weights to bf16 (Wih, Whh row-major; Wout transposed)
// ---------------------------------------------------------------------------
__global__ __launch_bounds__(256) void k_convert_w(
    const float* __restrict__ Wih, const float* __restrict__ Whh,
    const float* __restrict__ Wout,
    short* __restrict__ Wihb, short* __restrict__ Whhb, short* __restrict__ WoutTb)
{
    int idx = blockIdx.x * 256 + threadIdx.x;
    if (idx < 49152) {
        Wihb[idx] = f2bf(Wih[idx]);
    } else if (idx < 98304) {
        int e = idx - 49152;
        Whhb[e] = f2bf(Whh[e]);
    } else if (idx < 114688) {
        int e = idx - 98304;
        int o = e >> 7, k = e & 127;
        WoutTb[e] = f2bf(Wout[k * 128 + o]);   // WoutT[o][k]
    }
}

// ---------------------------------------------------------------------------
// Kernel 4: fused GRU (4 steps) + output projection, MFMA bf16.
// Block = 64 nodes, 4 waves; wave w owns nodes [nb+16w, nb+16w+16).
// Per wave: A-frag row m = lane&15 (node), k-group = lane>>4.
// C/D layout (verified): row=(lane>>4)*4+reg, col=lane&15.
// h kept in registers (h_reg[8][4]) between steps; routed via LDS (bf16)
// only to re-shape into the next step's A fragment.
// ---------------------------------------------------------------------------
__global__ __launch_bounds__(256, 2) void k_gru_fused(
    const float* __restrict__ v, const int* __restrict__ widx,
    const short* __restrict__ Wihb, const short* __restrict__ Whhb,
    const short* __restrict__ WoutTb,
    const float* __restrict__ bih, const float* __restrict__ bhh,
    const float* __restrict__ bout, float* __restrict__ out)
{
    __shared__ short x_bf[64][136];
    __shared__ short h_bf[64][136];
    int tid = threadIdx.x;
    int w = tid >> 6, lane = tid & 63;
    int c = lane & 15, q = lane >> 4;
    int nb = blockIdx.x * 64;

    float h_reg[8][4];
#pragma unroll
    for (int nt = 0; nt < 8; ++nt)
#pragma unroll
        for (int i = 0; i < 4; ++i) h_reg[nt][i] = 0.f;

    // zero h_bf for step 0 (h = 0; MFMA path is uniform across steps)
    {
        s16x8 z8 = {0, 0, 0, 0, 0, 0, 0, 0};
        for (int r0 = tid >> 4; r0 < 64; r0 += 16)
            *(s16x8*)&h_bf[r0][(tid & 15) * 8] = z8;
    }

    const short* bi_base = Wihb + c * 128 + q * 8;
    const short* bh_base = Whhb + c * 128 + q * 8;

    for (int t = 0; t < 1 + TSTEPS; ++t) {
        // ---- gather x_t = v[walk_idx[t]] -> bf16 LDS ----
        for (int r0 = tid >> 4; r0 < 64; r0 += 16) {
            int n = nb + r0;
            int src = (n < NN) ? widx[t * NN + n] : 0;
            const float4* vp = (const float4*)(v + (size_t)src * 128 + (tid & 15) * 8);
            float4 a = vp[0], b = vp[1];
            s16x8 xv;
            xv[0] = f2bf(a.x); xv[1] = f2bf(a.y); xv[2] = f2bf(a.z); xv[3] = f2bf(a.w);
            xv[4] = f2bf(b.x); xv[5] = f2bf(b.y); xv[6] = f2bf(b.z); xv[7] = f2bf(b.w);
            *(s16x8*)&x_bf[r0][(tid & 15) * 8] = xv;
        }
        __syncthreads();

        // ---- preload A fragments (all K for this wave's 16 nodes) ----
        s16x8 ax[4], ah[4];
#pragma unroll
        for (int ks = 0; ks < 4; ++ks) {
            ax[ks] = *(const s16x8*)&x_bf[w * 16 + c][ks * 32 + q * 8];
            ah[ks] = *(const s16x8*)&h_bf[w * 16 + c][ks * 32 + q * 8];
        }

        // ---- MFMA: gates. accRZ[0..7]=r (gi+gh summed), [8..15]=z,
        //      accIN/accHN = n-gate gi/gh kept separate ----
        f32x4 accRZ[16], accIN[8], accHN[8];
        f32x4 zf = {0.f, 0.f, 0.f, 0.f};
#pragma unroll
        for (int nt = 0; nt < 16; ++nt) accRZ[nt] = zf;
#pragma unroll
        for (int nt = 0; nt < 8; ++nt) { accIN[nt] = zf; accHN[nt] = zf; }

#pragma unroll
        for (int ks = 0; ks < 4; ++ks) {
#pragma unroll
            for (int nt = 0; nt < 16; ++nt) {
                s16x8 bi = *(const s16x8*)(bi_base + nt * 2048 + ks * 32);
                s16x8 bh = *(const s16x8*)(bh_base + nt * 2048 + ks * 32);
                accRZ[nt] = MFMA16(ax[ks], bi, accRZ[nt]);
                accRZ[nt] = MFMA16(ah[ks], bh, accRZ[nt]);
            }
#pragma unroll
            for (int nt = 0; nt < 8; ++nt) {
                s16x8 bi = *(const s16x8*)(bi_base + (16 + nt) * 2048 + ks * 32);
                s16x8 bh = *(const s16x8*)(bh_base + (16 + nt) * 2048 + ks * 32);
                accIN[nt] = MFMA16(ax[ks], bi, accIN[nt]);
                accHN[nt] = MFMA16(ah[ks], bh, accHN[nt]);
            }
        }

        // ---- epilogue: gate math in f32, h stays in registers ----
#pragma unroll
        for (int nt = 0; nt < 8; ++nt) {
            int u = nt * 16 + c;
            float b_r = bih[u] + bhh[u];
            float b_z = bih[128 + u] + bhh[128 + u];
            float bin_ = bih[256 + u];
            float bhn_ = bhh[256 + u];
#pragma unroll
            for (int i = 0; i < 4; ++i) {
                float r = 1.f / (1.f + expf(-(accRZ[nt][i] + b_r)));
                float z = 1.f / (1.f + expf(-(accRZ[8 + nt][i] + b_z)));
                float ng = tanhf(accIN[nt][i] + bin_ + r * (accHN[nt][i] + bhn_));
                float hn = (1.f - z) * ng + z * h_reg[nt][i];
                h_reg[nt][i] = hn;
                h_bf[w * 16 + q * 4 + i][u] = f2bf(hn);
            }
        }
        __syncthreads();
    }

    // ---- output projection: out = h @ Wout + bout ----
    s16x8 aout[4];
#pragma unroll
    for (int ks = 0; ks < 4; ++ks)
        aout[ks] = *(const s16x8*)&h_bf[w * 16 + c][ks * 32 + q * 8];

    f32x4 acco[8];
    f32x4 zf = {0.f, 0.f, 0.f, 0.f};
#pragma unroll
    for (int nt = 0; nt < 8; ++nt) acco[nt] = zf;

    const short* bo_base = WoutTb + c * 128 + q * 8;
#pragma unroll
    for (int ks = 0; ks < 4; ++ks)
#pragma unroll
        for (int nt = 0; nt < 8; ++nt) {
            s16x8 bo = *(const s16x8*)(bo_base + nt * 2048 + ks * 32);
            acco[nt] = MFMA16(aout[ks], bo, acco[nt]);
        }

#pragma unroll
    for (int nt = 0; nt < 8; ++nt) {
        int o = nt * 16 + c;
        float bb = bout[o];
#pragma unroll
        for (int i = 0; i < 4; ++i) {
            int n = nb + w * 16 + q * 4 + i;
            if (n < NN) out[(size_t)n * 128 + o] = acco[nt][i] + bb;
        }
    }
}

// ---------------------------------------------------------------------------
extern "C" void kernel_launch(void* const* d_in, const int* in_sizes, int n_in,
                              void* d_out, int out_size, void* d_ws, size_t ws_size,
                              hipStream_t stream)
{
    const float* node_attr = (const float*)d_in[0];
    const int*   edge_index = (const int*)d_in[1];
    const float* W1  = (const float*)d_in[3];
    const float* b1  = (const float*)d_in[4];
    const float* W2  = (const float*)d_in[5];
    const float* b2  = (const float*)d_in[6];
    const float* Wih = (const float*)d_in[7];
    const float* Whh = (const float*)d_in[8];
    const float* bih = (const float*)d_in[9];
    const float* bhh = (const float*)d_in[10];
    const float* Wout = (const float*)d_in[11];
    const float* bout = (const float*)d_in[12];
    const float* noise = (const float*)d_in[13];

    const int* dst = edge_index + (size_t)NN * DEGV;

    char* ws = (char*)d_ws;
    size_t offP    = 0;                               // N*256 f32 = 20.48 MB
    size_t offBase = offP + (size_t)NN * 256 * 4;     // N*64 f32  =  5.12 MB
    size_t offH    = offBase + (size_t)NN * 64 * 4;   // reused: bf16 weights
    size_t offWidx = offH + (size_t)NN * 128 * 4;     // 4*N int
    float* P    = (float*)(ws + offP);
    float* base = (float*)(ws + offBase);
    int*   widx = (int*)(ws + offWidx);
    short* Wihb   = (short*)(ws + offH);              // 384*128*2 = 96 KB
    short* Whhb   = Wihb + 384 * 128;
    short* WoutTb = Whhb + 384 * 128;                 // 128*128*2 = 32 KB

    dim3 blk(256);
    // weight conversion (independent of walks; runs first on the stream)
    k_convert_w<<<dim3(448), blk, 0, stream>>>(Wih, Whh, Wout, Wihb, Whhb, WoutTb);
    // per-node/per-slot scoring-MLP partials + init
    k_precompute<<<dim3(1250), blk, 0, stream>>>(node_attr, W1, b1, P, base, widx);
    // 3 walk-selection steps (sequential dependency)
    for (int t = 0; t < TSTEPS; ++t)
        k_walk_step<<<dim3(5000), blk, 0, stream>>>(P, base, dst, W2, b2, noise, widx, t);
    // fused GRU (4 steps) + output projection
    k_gru_fused<<<dim3(313), blk, 0, stream>>>(node_attr, widx, Wihb, Whhb, WoutTb,
                                               bih, bhh, bout, (float*)d_out);
}

// Round 3
// 474.518 us; speedup vs baseline: 6.5953x; 1.3659x over previous
//
#include <hip/hip_runtime.h>
#include <hip/hip_bf16.h>
#include <math.h>

#define NN 20000
#define DEGV 16
#define CINV 128
#define TSTEPS 3
#define HIDV 128

typedef float f32x4 __attribute__((ext_vector_type(4)));
typedef short s16x8 __attribute__((ext_vector_type(8)));

#define MFMA16(a, b, c) __builtin_amdgcn_mfma_f32_16x16x32_bf16(a, b, c, 0, 0, 0)

static __device__ __forceinline__ short f2bf(float x) {
    __hip_bfloat16 h = __float2bfloat16(x);
    return *reinterpret_cast<short*>(&h);
}

// ---------------------------------------------------------------------------
// Kernel 1: P[s][n][j] = sum_k v[n][k] * W1[(s*128+k)*64 + j]   (slot-major!)
// also init base[n][j] = P[0][n][j] + b1[j], walk_idx[0][n] = n
// ---------------------------------------------------------------------------
__global__ __launch_bounds__(256) void k_precompute(
    const float* __restrict__ v, const float* __restrict__ W1,
    const float* __restrict__ b1,
    float* __restrict__ P, float* __restrict__ base, int* __restrict__ walk_idx)
{
    __shared__ float vt[16][132];
    int nb = blockIdx.x * 16;
    for (int idx = threadIdx.x; idx < 16 * 128; idx += 256) {
        int nl = idx >> 7, k = idx & 127;
        int n = nb + nl;
        vt[nl][k] = (n < NN) ? v[n * 128 + k] : 0.f;
    }
    __syncthreads();
    int s = threadIdx.x >> 6;
    int j = threadIdx.x & 63;
    double acc[16];
#pragma unroll
    for (int nl = 0; nl < 16; ++nl) acc[nl] = 0.0;
    for (int k = 0; k < 128; ++k) {
        double w = (double)W1[(s * 128 + k) * 64 + j];
#pragma unroll
        for (int nl = 0; nl < 16; ++nl)
            acc[nl] = fma((double)vt[nl][k], w, acc[nl]);
    }
    for (int nl = 0; nl < 16; ++nl) {
        int n = nb + nl;
        if (n < NN) {
            float pv = (float)acc[nl];
            P[(size_t)s * NN * 64 + n * 64 + j] = pv;
            if (s == 0) {
                base[n * 64 + j] = pv + b1[j];
                if (j == 0) walk_idx[n] = n;
            }
        }
    }
}

// ---------------------------------------------------------------------------
// Kernel 2: one walk selection step. One 64-lane wave per node.
//   lane = d*4 + sub : candidate d (0..15), sub-slice sub (0..3) of 64-dim dot
//   P gathered from slice (t+1): 5.1 MB working set (L2-friendly)
// ---------------------------------------------------------------------------
__global__ __launch_bounds__(256) void k_walk_step(
    const float* __restrict__ P, float* __restrict__ base,
    const int* __restrict__ dst, const float* __restrict__ W2,
    const float* __restrict__ b2, const float* __restrict__ noise,
    int* __restrict__ walk_idx, int t)
{
    int wave = threadIdx.x >> 6;
    int lane = threadIdx.x & 63;
    int n = blockIdx.x * 4 + wave;
    if (n >= NN) return;

    int wl = walk_idx[t * NN + n];
    int d = lane >> 2, sub = lane & 3;
    int cand = dst[wl * DEGV + d];

    const float* Pslice = P + (size_t)(t + 1) * NN * 64;
    const float4* b4 = (const float4*)(base + (size_t)n * 64);
    const float4* p4 = (const float4*)(Pslice + (size_t)cand * 64);
    const float4* w4 = (const float4*)W2;

    double acc = 0.0;
#pragma unroll
    for (int k = 0; k < 4; ++k) {
        float4 bb = b4[sub * 4 + k];
        float4 pp = p4[sub * 4 + k];
        float4 ww = w4[sub * 4 + k];
        acc += (double)fmaxf(bb.x + pp.x, 0.f) * (double)ww.x;
        acc += (double)fmaxf(bb.y + pp.y, 0.f) * (double)ww.y;
        acc += (double)fmaxf(bb.z + pp.z, 0.f) * (double)ww.z;
        acc += (double)fmaxf(bb.w + pp.w, 0.f) * (double)ww.w;
    }
    acc += __shfl_xor(acc, 1);
    acc += __shfl_xor(acc, 2);
    double logp = acc + (double)b2[0];

    double m = logp;
    for (int mask = 4; mask < 64; mask <<= 1) m = fmax(m, __shfl_xor(m, mask));
    double e = exp(logp - m);
    double ssum = e;
    for (int mask = 4; mask < 64; mask <<= 1) ssum += __shfl_xor(ssum, mask);
    double norm = m + log(ssum);

    double wp = exp(logp - norm) +
                0.01 * (double)noise[((size_t)t * NN + n) * DEGV + d];

    int bd = d;
    double bwp = wp;
    for (int mask = 4; mask < 64; mask <<= 1) {
        double owp = __shfl_xor(bwp, mask);
        int od = __shfl_xor(bd, mask);
        if (owp > bwp || (owp == bwp && od < bd)) { bwp = owp; bd = od; }
    }
    int sel = dst[wl * DEGV + bd];

    base[(size_t)n * 64 + lane] += Pslice[(size_t)sel * 64 + lane];
    if (lane == 0) walk_idx[(t + 1) * NN + n] = sel;
}

// ---------------------------------------------------------------------------
// Kernel 3: convert weights to bf16 (Wih, Whh row-major; Wout transposed)
// ---------------------------------------------------------------------------
__global__ __launch_bounds__(256) void k_convert_w(
    const float* __restrict__ Wih, const float* __restrict__ Whh,
    const float* __restrict__ Wout,
    short* __restrict__ Wihb, short* __restrict__ Whhb, short* __restrict__ WoutTb)
{
    int idx = blockIdx.x * 256 + threadIdx.x;
    if (idx < 49152) {
        Wihb[idx] = f2bf(Wih[idx]);
    } else if (idx < 98304) {
        int e = idx - 49152;
        Whhb[e] = f2bf(Whh[e]);
    } else if (idx < 114688) {
        int e = idx - 98304;
        int o = e >> 7, k = e & 127;
        WoutTb[e] = f2bf(Wout[k * 128 + o]);   // WoutT[o][k]
    }
}

// ---------------------------------------------------------------------------
// Kernel 4: fused GRU (4 steps) + output projection, MFMA bf16.
// ONE WAVE per block, 16 nodes. Grid = 1250 (exactly 20000/16).
// Gate-tile-outer loop: only 4 f32x4 accumulators live at a time (no spill).
// A-frag: row=lane&15 (node), k=(lane>>4)*8 within each K=32 chunk.
// C/D layout (verified): row=(lane>>4)*4+reg, col=lane&15.
// ---------------------------------------------------------------------------
__global__ __launch_bounds__(64) void k_gru_fused(
    const float* __restrict__ v, const int* __restrict__ widx,
    const short* __restrict__ Wihb, const short* __restrict__ Whhb,
    const short* __restrict__ WoutTb,
    const float* __restrict__ bih, const float* __restrict__ bhh,
    const float* __restrict__ bout, float* __restrict__ out)
{
    __shared__ short x_bf[16][136];
    __shared__ short h_bf[16][136];
    int lane = threadIdx.x;
    int c = lane & 15, q = lane >> 4;
    int nb = blockIdx.x * 16;

    // hoisted biases (statically indexed -> registers)
    float b_r[8], b_z[8], b_in[8], b_hn[8];
#pragma unroll
    for (int nt = 0; nt < 8; ++nt) {
        int u = nt * 16 + c;
        b_r[nt]  = bih[u] + bhh[u];
        b_z[nt]  = bih[128 + u] + bhh[128 + u];
        b_in[nt] = bih[256 + u];
        b_hn[nt] = bhh[256 + u];
    }

    float h_reg[8][4];           // h[row=q*4+i][col=nt*16+c]
    s16x8 ah[4];                 // h A-fragments (zero for step 0)
    s16x8 z8 = {0, 0, 0, 0, 0, 0, 0, 0};
#pragma unroll
    for (int nt = 0; nt < 8; ++nt)
#pragma unroll
        for (int i = 0; i < 4; ++i) h_reg[nt][i] = 0.f;
#pragma unroll
    for (int ks = 0; ks < 4; ++ks) ah[ks] = z8;

    const short* bi_base = Wihb + c * 128 + q * 8;
    const short* bh_base = Whhb + c * 128 + q * 8;

    for (int t = 0; t < 1 + TSTEPS; ++t) {
        // ---- gather x_t = v[walk_idx[t]] -> bf16 LDS (lane: row c, chunk q) ----
        {
            int src = widx[t * NN + nb + c];
            const float4* vp = (const float4*)(v + (size_t)src * 128 + q * 32);
#pragma unroll
            for (int kk = 0; kk < 4; ++kk) {
                float4 a = vp[2 * kk], b = vp[2 * kk + 1];
                s16x8 xv;
                xv[0] = f2bf(a.x); xv[1] = f2bf(a.y); xv[2] = f2bf(a.z); xv[3] = f2bf(a.w);
                xv[4] = f2bf(b.x); xv[5] = f2bf(b.y); xv[6] = f2bf(b.z); xv[7] = f2bf(b.w);
                *(s16x8*)&x_bf[c][q * 32 + kk * 8] = xv;
            }
        }
        __syncthreads();

        s16x8 ax[4];
#pragma unroll
        for (int ks = 0; ks < 4; ++ks)
            ax[ks] = *(const s16x8*)&x_bf[c][ks * 32 + q * 8];

        // ---- gate tiles: r/z/in/hn for 16 output cols at a time ----
#pragma unroll
        for (int nt = 0; nt < 8; ++nt) {
            f32x4 aR = {0.f, 0.f, 0.f, 0.f}, aZ = aR, aIN = aR, aHN = aR;
#pragma unroll
            for (int ks = 0; ks < 4; ++ks) {
                s16x8 biR = *(const s16x8*)(bi_base + nt * 2048 + ks * 32);
                s16x8 bhR = *(const s16x8*)(bh_base + nt * 2048 + ks * 32);
                s16x8 biZ = *(const s16x8*)(bi_base + (8 + nt) * 2048 + ks * 32);
                s16x8 bhZ = *(const s16x8*)(bh_base + (8 + nt) * 2048 + ks * 32);
                s16x8 biN = *(const s16x8*)(bi_base + (16 + nt) * 2048 + ks * 32);
                s16x8 bhN = *(const s16x8*)(bh_base + (16 + nt) * 2048 + ks * 32);
                aR  = MFMA16(ax[ks], biR, aR);
                aR  = MFMA16(ah[ks], bhR, aR);
                aZ  = MFMA16(ax[ks], biZ, aZ);
                aZ  = MFMA16(ah[ks], bhZ, aZ);
                aIN = MFMA16(ax[ks], biN, aIN);
                aHN = MFMA16(ah[ks], bhN, aHN);
            }
            // epilogue for this tile (f32 gate math, h stays in regs)
#pragma unroll
            for (int i = 0; i < 4; ++i) {
                float r = 1.f / (1.f + expf(-(aR[i] + b_r[nt])));
                float z = 1.f / (1.f + expf(-(aZ[i] + b_z[nt])));
                float ng = tanhf(aIN[i] + b_in[nt] + r * (aHN[i] + b_hn[nt]));
                float hn = (1.f - z) * ng + z * h_reg[nt][i];
                h_reg[nt][i] = hn;
                h_bf[q * 4 + i][nt * 16 + c] = f2bf(hn);
            }
        }
        __syncthreads();

        // ---- reload h fragments (transposed view) for next step / output ----
#pragma unroll
        for (int ks = 0; ks < 4; ++ks)
            ah[ks] = *(const s16x8*)&h_bf[c][ks * 32 + q * 8];
    }

    // ---- output projection: out = h @ Wout + bout ----
    const short* bo_base = WoutTb + c * 128 + q * 8;
#pragma unroll
    for (int nt = 0; nt < 8; ++nt) {
        f32x4 acco = {0.f, 0.f, 0.f, 0.f};
#pragma unroll
        for (int ks = 0; ks < 4; ++ks) {
            s16x8 bo = *(const s16x8*)(bo_base + nt * 2048 + ks * 32);
            acco = MFMA16(ah[ks], bo, acco);
        }
        int o = nt * 16 + c;
        float bb = bout[o];
#pragma unroll
        for (int i = 0; i < 4; ++i)
            out[(size_t)(nb + q * 4 + i) * 128 + o] = acco[i] + bb;
    }
}

// ---------------------------------------------------------------------------
extern "C" void kernel_launch(void* const* d_in, const int* in_sizes, int n_in,
                              void* d_out, int out_size, void* d_ws, size_t ws_size,
                              hipStream_t stream)
{
    const float* node_attr = (const float*)d_in[0];
    const int*   edge_index = (const int*)d_in[1];
    const float* W1  = (const float*)d_in[3];
    const float* b1  = (const float*)d_in[4];
    const float* W2  = (const float*)d_in[5];
    const float* b2  = (const float*)d_in[6];
    const float* Wih = (const float*)d_in[7];
    const float* Whh = (const float*)d_in[8];
    const float* bih = (const float*)d_in[9];
    const float* bhh = (const float*)d_in[10];
    const float* Wout = (const float*)d_in[11];
    const float* bout = (const float*)d_in[12];
    const float* noise = (const float*)d_in[13];

    const int* dst = edge_index + (size_t)NN * DEGV;

    char* ws = (char*)d_ws;
    size_t offP    = 0;                               // 4*N*64 f32 = 20.48 MB
    size_t offBase = offP + (size_t)4 * NN * 64 * 4;  // N*64 f32   =  5.12 MB
    size_t offW    = offBase + (size_t)NN * 64 * 4;   // bf16 weights
    size_t offWidx = offW + (size_t)(2 * 49152 + 16384) * 2;
    float* P    = (float*)(ws + offP);
    float* base = (float*)(ws + offBase);
    short* Wihb   = (short*)(ws + offW);              // 384*128*2 = 96 KB
    short* Whhb   = Wihb + 384 * 128;
    short* WoutTb = Whhb + 384 * 128;                 // 128*128*2 = 32 KB
    int*   widx = (int*)(ws + offWidx);               // 4*N int

    dim3 blk(256);
    // weight conversion (independent of walks; runs first on the stream)
    k_convert_w<<<dim3(448), blk, 0, stream>>>(Wih, Whh, Wout, Wihb, Whhb, WoutTb);
    // per-node/per-slot scoring-MLP partials + init
    k_precompute<<<dim3(1250), blk, 0, stream>>>(node_attr, W1, b1, P, base, widx);
    // 3 walk-selection steps (sequential dependency)
    for (int t = 0; t < TSTEPS; ++t)
        k_walk_step<<<dim3(5000), blk, 0, stream>>>(P, base, dst, W2, b2, noise, widx, t);
    // fused GRU (4 steps) + output projection (1 wave / 16 nodes per block)
    k_gru_fused<<<dim3(1250), dim3(64), 0, stream>>>(node_attr, widx, Wihb, Whhb, WoutTb,
                                                     bih, bhh, bout, (float*)d_out);
}

// Round 5
// 222.668 us; speedup vs baseline: 14.0549x; 2.1311x over previous
//
#include <hip/hip_runtime.h>
#include <hip/hip_bf16.h>
#include <math.h>

#define NN 20000
#define DEGV 16
#define CINV 128
#define TSTEPS 3
#define HIDV 128

typedef float f32x4 __attribute__((ext_vector_type(4)));
typedef short s16x8 __attribute__((ext_vector_type(8)));

#define MFMA16(a, b, c) __builtin_amdgcn_mfma_f32_16x16x32_bf16(a, b, c, 0, 0, 0)

static __device__ __forceinline__ short f2bf(float x) {
    __hip_bfloat16 h = __float2bfloat16(x);
    return *reinterpret_cast<short*>(&h);
}

// ---------------------------------------------------------------------------
// Kernel 1: P[s][n][j] = sum_k v[n][k] * W1[(s*128+k)*64 + j]   (slot-major)
// also init base[n][j] = P[0][n][j] + b1[j], walk_idx[0][n] = n
// ---------------------------------------------------------------------------
__global__ __launch_bounds__(256) void k_precompute(
    const float* __restrict__ v, const float* __restrict__ W1,
    const float* __restrict__ b1,
    float* __restrict__ P, float* __restrict__ base, int* __restrict__ walk_idx)
{
    __shared__ float vt[16][132];
    int nb = blockIdx.x * 16;
    for (int idx = threadIdx.x; idx < 16 * 128; idx += 256) {
        int nl = idx >> 7, k = idx & 127;
        int n = nb + nl;
        vt[nl][k] = (n < NN) ? v[n * 128 + k] : 0.f;
    }
    __syncthreads();
    int s = threadIdx.x >> 6;
    int j = threadIdx.x & 63;
    double acc[16];
#pragma unroll
    for (int nl = 0; nl < 16; ++nl) acc[nl] = 0.0;
    for (int k = 0; k < 128; ++k) {
        double w = (double)W1[(s * 128 + k) * 64 + j];
#pragma unroll
        for (int nl = 0; nl < 16; ++nl)
            acc[nl] = fma((double)vt[nl][k], w, acc[nl]);
    }
    for (int nl = 0; nl < 16; ++nl) {
        int n = nb + nl;
        if (n < NN) {
            float pv = (float)acc[nl];
            P[(size_t)s * NN * 64 + n * 64 + j] = pv;
            if (s == 0) {
                base[n * 64 + j] = pv + b1[j];
                if (j == 0) walk_idx[n] = n;
            }
        }
    }
}

// ---------------------------------------------------------------------------
// Kernel 2: one walk selection step. One 64-lane wave per node.
// ---------------------------------------------------------------------------
__global__ __launch_bounds__(256) void k_walk_step(
    const float* __restrict__ P, float* __restrict__ base,
    const int* __restrict__ dst, const float* __restrict__ W2,
    const float* __restrict__ b2, const float* __restrict__ noise,
    int* __restrict__ walk_idx, int t)
{
    int wave = threadIdx.x >> 6;
    int lane = threadIdx.x & 63;
    int n = blockIdx.x * 4 + wave;
    if (n >= NN) return;

    int wl = walk_idx[t * NN + n];
    int d = lane >> 2, sub = lane & 3;
    int cand = dst[wl * DEGV + d];

    const float* Pslice = P + (size_t)(t + 1) * NN * 64;
    const float4* b4 = (const float4*)(base + (size_t)n * 64);
    const float4* p4 = (const float4*)(Pslice + (size_t)cand * 64);
    const float4* w4 = (const float4*)W2;

    double acc = 0.0;
#pragma unroll
    for (int k = 0; k < 4; ++k) {
        float4 bb = b4[sub * 4 + k];
        float4 pp = p4[sub * 4 + k];
        float4 ww = w4[sub * 4 + k];
        acc += (double)fmaxf(bb.x + pp.x, 0.f) * (double)ww.x;
        acc += (double)fmaxf(bb.y + pp.y, 0.f) * (double)ww.y;
        acc += (double)fmaxf(bb.z + pp.z, 0.f) * (double)ww.z;
        acc += (double)fmaxf(bb.w + pp.w, 0.f) * (double)ww.w;
    }
    acc += __shfl_xor(acc, 1);
    acc += __shfl_xor(acc, 2);
    double logp = acc + (double)b2[0];

    double m = logp;
    for (int mask = 4; mask < 64; mask <<= 1) m = fmax(m, __shfl_xor(m, mask));
    double e = exp(logp - m);
    double ssum = e;
    for (int mask = 4; mask < 64; mask <<= 1) ssum += __shfl_xor(ssum, mask);
    double norm = m + log(ssum);

    double wp = exp(logp - norm) +
                0.01 * (double)noise[((size_t)t * NN + n) * DEGV + d];

    int bd = d;
    double bwp = wp;
    for (int mask = 4; mask < 64; mask <<= 1) {
        double owp = __shfl_xor(bwp, mask);
        int od = __shfl_xor(bd, mask);
        if (owp > bwp || (owp == bwp && od < bd)) { bwp = owp; bd = od; }
    }
    int sel = dst[wl * DEGV + bd];

    base[(size_t)n * 64 + lane] += Pslice[(size_t)sel * 64 + lane];
    if (lane == 0) walk_idx[(t + 1) * NN + n] = sel;
}

// ---------------------------------------------------------------------------
// Kernel 3: convert weights to bf16 (Wih, Whh row-major; Wout transposed)
// ---------------------------------------------------------------------------
__global__ __launch_bounds__(256) void k_convert_w(
    const float* __restrict__ Wih, const float* __restrict__ Whh,
    const float* __restrict__ Wout,
    short* __restrict__ Wihb, short* __restrict__ Whhb, short* __restrict__ WoutTb)
{
    int idx = blockIdx.x * 256 + threadIdx.x;
    if (idx < 49152) {
        Wihb[idx] = f2bf(Wih[idx]);
    } else if (idx < 98304) {
        int e = idx - 49152;
        Whhb[e] = f2bf(Whh[e]);
    } else if (idx < 114688) {
        int e = idx - 98304;
        int o = e >> 7, k = e & 127;
        WoutTb[e] = f2bf(Wout[k * 128 + o]);   // WoutT[o][k]
    }
}

// ---------------------------------------------------------------------------
// Kernel 4: fused GRU (4 steps) + output projection, MFMA bf16.
// Block = 256 threads (4 waves), 16 nodes per block. Grid = 1250.
// TILE SPLIT ACROSS WAVES: wave w owns gate-column tiles nt = {2w, 2w+1}
// (h-columns 32w..32w+31) and, in the epilogue, o-tiles {2w, 2w+1} ONLY.
// Peak live regs/wave ~130 -> no spill.
// h' recombined through bf16 LDS each step (also the A-frag transpose).
// A-frag: row=lane&15 (node), k=(lane>>4)*8 within each K=32 chunk.
// C/D layout (verified): row=(lane>>4)*4+reg, col=lane&15.
// ---------------------------------------------------------------------------
__global__ __launch_bounds__(256, 2) void k_gru_fused(
    const float* __restrict__ v, const int* __restrict__ widx,
    const short* __restrict__ Wihb, const short* __restrict__ Whhb,
    const short* __restrict__ WoutTb,
    const float* __restrict__ bih, const float* __restrict__ bhh,
    const float* __restrict__ bout, float* __restrict__ out)
{
    __shared__ short x_bf[16][136];
    __shared__ short h_bf[16][136];
    int tid = threadIdx.x;
    int w = tid >> 6, lane = tid & 63;
    int c = lane & 15, q = lane >> 4;
    int nb = blockIdx.x * 16;

    // hoisted biases for this wave's two tiles
    float b_r[2], b_z[2], b_in[2], b_hn[2];
#pragma unroll
    for (int nt = 0; nt < 2; ++nt) {
        int u = (2 * w + nt) * 16 + c;
        b_r[nt]  = bih[u] + bhh[u];
        b_z[nt]  = bih[128 + u] + bhh[128 + u];
        b_in[nt] = bih[256 + u];
        b_hn[nt] = bhh[256 + u];
    }

    float h_reg[2][4];           // h[row=q*4+i][col=(2w+nt)*16+c]
    s16x8 ah[4];
    s16x8 z8 = {0, 0, 0, 0, 0, 0, 0, 0};
#pragma unroll
    for (int nt = 0; nt < 2; ++nt)
#pragma unroll
        for (int i = 0; i < 4; ++i) h_reg[nt][i] = 0.f;
#pragma unroll
    for (int ks = 0; ks < 4; ++ks) ah[ks] = z8;

    const short* bi_base = Wihb + c * 128 + q * 8;
    const short* bh_base = Whhb + c * 128 + q * 8;

#pragma unroll 1
    for (int t = 0; t < 1 + TSTEPS; ++t) {
        // ---- gather x_t = v[walk_idx[t]] -> bf16 LDS (256 thr: row=tid>>4, chunk=tid&15) ----
        {
            int row = tid >> 4, chunk = tid & 15;
            int src = widx[t * NN + nb + row];
            const float4* vp = (const float4*)(v + (size_t)src * 128 + chunk * 8);
            float4 a = vp[0], b = vp[1];
            s16x8 xv;
            xv[0] = f2bf(a.x); xv[1] = f2bf(a.y); xv[2] = f2bf(a.z); xv[3] = f2bf(a.w);
            xv[4] = f2bf(b.x); xv[5] = f2bf(b.y); xv[6] = f2bf(b.z); xv[7] = f2bf(b.w);
            *(s16x8*)&x_bf[row][chunk * 8] = xv;
        }
        __syncthreads();

        s16x8 ax[4];
#pragma unroll
        for (int ks = 0; ks < 4; ++ks)
            ax[ks] = *(const s16x8*)&x_bf[c][ks * 32 + q * 8];

        // ---- this wave's two gate tiles ----
#pragma unroll
        for (int nt = 0; nt < 2; ++nt) {
            int tr = 2 * w + nt;          // tile index (0..7)
            f32x4 aR = {0.f, 0.f, 0.f, 0.f}, aZ = aR, aIN = aR, aHN = aR;
#pragma unroll
            for (int ks = 0; ks < 4; ++ks) {
                s16x8 biR = *(const s16x8*)(bi_base + tr * 2048 + ks * 32);
                s16x8 bhR = *(const s16x8*)(bh_base + tr * 2048 + ks * 32);
                s16x8 biZ = *(const s16x8*)(bi_base + (8 + tr) * 2048 + ks * 32);
                s16x8 bhZ = *(const s16x8*)(bh_base + (8 + tr) * 2048 + ks * 32);
                s16x8 biN = *(const s16x8*)(bi_base + (16 + tr) * 2048 + ks * 32);
                s16x8 bhN = *(const s16x8*)(bh_base + (16 + tr) * 2048 + ks * 32);
                aR  = MFMA16(ax[ks], biR, aR);
                aR  = MFMA16(ah[ks], bhR, aR);
                aZ  = MFMA16(ax[ks], biZ, aZ);
                aZ  = MFMA16(ah[ks], bhZ, aZ);
                aIN = MFMA16(ax[ks], biN, aIN);
                aHN = MFMA16(ah[ks], bhN, aHN);
            }
#pragma unroll
            for (int i = 0; i < 4; ++i) {
                float r = 1.f / (1.f + expf(-(aR[i] + b_r[nt])));
                float z = 1.f / (1.f + expf(-(aZ[i] + b_z[nt])));
                float ng = tanhf(aIN[i] + b_in[nt] + r * (aHN[i] + b_hn[nt]));
                float hn = (1.f - z) * ng + z * h_reg[nt][i];
                h_reg[nt][i] = hn;
                h_bf[q * 4 + i][tr * 16 + c] = f2bf(hn);
            }
        }
        __syncthreads();

        // ---- reload full-h fragments (transposed view) for next step / output ----
#pragma unroll
        for (int ks = 0; ks < 4; ++ks)
            ah[ks] = *(const s16x8*)&h_bf[c][ks * 32 + q * 8];
    }

    // ---- output projection: wave w handles EXACTLY o-tiles {2w, 2w+1} ----
    const short* bo_base = WoutTb + c * 128 + q * 8;
#pragma unroll
    for (int nt = 0; nt < 2; ++nt) {
        int ot = 2 * w + nt;              // 0..7 across the 4 waves
        f32x4 acco = {0.f, 0.f, 0.f, 0.f};
#pragma unroll
        for (int ks = 0; ks < 4; ++ks) {
            s16x8 bo = *(const s16x8*)(bo_base + ot * 2048 + ks * 32);
            acco = MFMA16(ah[ks], bo, acco);
        }
        int o = ot * 16 + c;
        float bb = bout[o];
#pragma unroll
        for (int i = 0; i < 4; ++i)
            out[(size_t)(nb + q * 4 + i) * 128 + o] = acco[i] + bb;
    }
}

// ---------------------------------------------------------------------------
extern "C" void kernel_launch(void* const* d_in, const int* in_sizes, int n_in,
                              void* d_out, int out_size, void* d_ws, size_t ws_size,
                              hipStream_t stream)
{
    const float* node_attr = (const float*)d_in[0];
    const int*   edge_index = (const int*)d_in[1];
    const float* W1  = (const float*)d_in[3];
    const float* b1  = (const float*)d_in[4];
    const float* W2  = (const float*)d_in[5];
    const float* b2  = (const float*)d_in[6];
    const float* Wih = (const float*)d_in[7];
    const float* Whh = (const float*)d_in[8];
    const float* bih = (const float*)d_in[9];
    const float* bhh = (const float*)d_in[10];
    const float* Wout = (const float*)d_in[11];
    const float* bout = (const float*)d_in[12];
    const float* noise = (const float*)d_in[13];

    const int* dst = edge_index + (size_t)NN * DEGV;

    char* ws = (char*)d_ws;
    size_t offP    = 0;                               // 4*N*64 f32 = 20.48 MB
    size_t offBase = offP + (size_t)4 * NN * 64 * 4;  // N*64 f32   =  5.12 MB
    size_t offW    = offBase + (size_t)NN * 64 * 4;   // bf16 weights
    size_t offWidx = offW + (size_t)(2 * 49152 + 16384) * 2;
    float* P    = (float*)(ws + offP);
    float* base = (float*)(ws + offBase);
    short* Wihb   = (short*)(ws + offW);              // 384*128*2 = 96 KB
    short* Whhb   = Wihb + 384 * 128;
    short* WoutTb = Whhb + 384 * 128;                 // 128*128*2 = 32 KB
    int*   widx = (int*)(ws + offWidx);               // 4*N int

    dim3 blk(256);
    k_convert_w<<<dim3(448), blk, 0, stream>>>(Wih, Whh, Wout, Wihb, Whhb, WoutTb);
    k_precompute<<<dim3(1250), blk, 0, stream>>>(node_attr, W1, b1, P, base, widx);
    for (int t = 0; t < TSTEPS; ++t)
        k_walk_step<<<dim3(5000), blk, 0, stream>>>(P, base, dst, W2, b2, noise, widx, t);
    k_gru_fused<<<dim3(1250), blk, 0, stream>>>(node_attr, widx, Wihb, Whhb, WoutTb,
                                                bih, bhh, bout, (float*)d_out);
}